// Round 14
// baseline (1806.913 us; speedup 1.0000x reference)
//
#include <hip/hip_runtime.h>
#include <hip/hip_bf16.h>
#include <stdint.h>

#define NB    256   // batch / segments
#define CIN   128   // input channels
#define HID   256   // hidden
#define TST   256   // only first 256 timesteps matter for the output
#define NCLS  400

#define GRPS  16    // batch groups
#define MEMB  4     // blocks per group (hidden-slice members)
#define BPG   16    // batches per group
#define HPB   64    // hidden units per block
#define RPB   256   // gate rows per block (4 gates x 64 hid)
#define HXS   392   // s_hxb row stride in SHORTS (384 + 8 pad)
#define SPP   17    // s_part row stride in floats

// ---- workspace layout (bytes) ----
#define WS_SUMS   0u         // 256*128*4 = 131072
#define WS_HEX0   131072u    // u64[256][64] bf16-packed h0
#define WS_HEXS   262144u    // u64[2][256][64] SLOW mirror ring (agent scope) = 262144
#define WS_ENT    524288u    // 16 entry counters x 64B = 1024 (memset with HEXS)
#define WS_HEXF   528384u    // u64[2][256][64] FAST ring (sc0 / XCD-L2 scope)
#define WS_C0     790528u    // 256*256*4
#define WS_PP     1052672u   // 256*16*4*64*4 = 4194304 masked partials

typedef __attribute__((ext_vector_type(8))) short bf16x8;  // 8 bf16 = one MFMA A/B frag
typedef __attribute__((ext_vector_type(4))) float f32x4;   // MFMA accumulator
typedef unsigned long long u64;

__device__ __forceinline__ short f2bf(float f) {
  __hip_bfloat16 h = __float2bfloat16(f);
  return *reinterpret_cast<short*>(&h);
}
__device__ __forceinline__ float sigm(float v) { return 1.0f / (1.0f + __expf(-v)); }
__device__ __forceinline__ float tanh_(float v) {
  v = fminf(fmaxf(v, -15.0f), 15.0f);
  const float e = __expf(2.0f * v);
  return (e - 1.0f) / (e + 1.0f);
}
// 12-bit signed fixed-point in (-1,1): abs err <= 2.44e-4 (< bf16 ulp near 1)
__device__ __forceinline__ int q12(float h) {
  int q = (int)rintf(h * 2048.f);
  q = max(-2048, min(2047, q));
  return q & 0xFFF;
}
__device__ __forceinline__ short dq12(int bits) {
  int q = (bits ^ 0x800) - 0x800;           // sign-extend 12-bit
  return f2bf((float)q * (1.0f / 2048.f));
}

// sc0-only global ops: bypass L1, serviced at the XCD's L2 (NOT written through to
// the device coherence point). Only valid as a FAST PATH between blocks on the
// same XCD; every use below is paired with an agent-scope fallback/mirror.
__device__ __forceinline__ void st_sc0(u64* p, u64 v) {
  asm volatile("global_store_dwordx2 %0, %1, off sc0" :: "v"(p), "v"(v) : "memory");
}
__device__ __forceinline__ u64 ld_sc0(const u64* p) {
  u64 v;
  asm volatile("global_load_dwordx2 %0, %1, off sc0\n\ts_waitcnt vmcnt(0)"
               : "=v"(v) : "v"(p));
  return v;
}

// ---------------- segment sums (the "input_means" that are really sums) ----------------
__global__ void k_segsum(const float* __restrict__ x, const int* __restrict__ lens,
                         float* __restrict__ sums) {
  const int b = blockIdx.x, t = threadIdx.x;
  __shared__ int   s_l[NB];
  __shared__ int   s_red[256];
  __shared__ float s_f[CIN];
  s_l[t] = lens[t];
  __syncthreads();
  int part = 0;
  for (int i = t; i < b; i += 256) part += s_l[i];
  s_red[t] = part; __syncthreads();
  for (int k = 128; k > 0; k >>= 1) { if (t < k) s_red[t] += s_red[t + k]; __syncthreads(); }
  const int off = s_red[0];
  const int len = s_l[b];
  const int c = t & 127, half = t >> 7;
  float a = 0.f;
  for (int r = half; r < len; r += 2) a += x[(size_t)(off + r) * CIN + c];
  if (half) s_f[c] = a;
  __syncthreads();
  if (!half) sums[b * CIN + c] = a + s_f[c];
}

// ---------------- h0 = relu(sums@W1h^T)@W2h^T ; c0 likewise ----------------
__global__ void k_init(const float* __restrict__ sums,
                       const float* __restrict__ w1h, const float* __restrict__ w2h,
                       const float* __restrict__ w1c, const float* __restrict__ w2c,
                       u64* __restrict__ hex0, float* __restrict__ c0) {
  const int b = blockIdx.x, t = threadIdx.x;
  __shared__ float s_in[CIN], s_h[CIN], s_c[CIN];
  __shared__ __align__(8) short s_hb[HID];
  if (t < CIN) s_in[t] = sums[b * CIN + t];
  __syncthreads();
  {
    const int j = t & 127;
    const float* w = (t < CIN ? w1h : w1c) + j * CIN;
    float a = 0.f;
    #pragma unroll 8
    for (int k = 0; k < CIN; k++) a += s_in[k] * w[k];
    a = fmaxf(a, 0.f);
    if (t < CIN) s_h[j] = a; else s_c[j] = a;
  }
  __syncthreads();
  float ah = 0.f, ac = 0.f;
  const float* wh = w2h + t * CIN;
  const float* wc = w2c + t * CIN;
  #pragma unroll 8
  for (int k = 0; k < CIN; k++) { ah += s_h[k] * wh[k]; ac += s_c[k] * wc[k]; }
  s_hb[t] = f2bf(ah);
  c0[b * HID + t] = ac;
  __syncthreads();
  if (t < HID / 4)
    hex0[(size_t)b * 64 + t] = *(const u64*)&s_hb[t * 4];
}

// ---------------- persistent LSTM recurrence (MFMA, XCD-local L2 exchange) ----------------
// 64 blocks x 1024 threads = 16 groups (16 batches) x 4 members (64 hid = 256 rows).
// R13 lesson: agent-scope exchange = MALL RTT ~1us; store->poll chain ~2.4us/step
// dominates. Group members (blockIdx stride 16 == 0 mod 8) share an XCD L2 under
// the measured round-robin mapping -> exchange via sc0 ops at THAT L2 (~0.15us).
// Mapping is officially undefined, so: producers DOUBLE-publish (sc0 hexF + agent
// hexS mirror); consumers poll hexF 32x then fall back to agent hexS forever.
// Stale-tag hazard across graph replays: consumers zero their own hexF poll region
// in-kernel (sc0), sealed by a one-time per-group agent barrier; hexS is memset.
__launch_bounds__(1024, 1)
__global__ void k_lstm(const float* __restrict__ x, const int* __restrict__ lens,
                       const float* __restrict__ Wih, const float* __restrict__ Whh,
                       const float* __restrict__ bih, const float* __restrict__ bhh,
                       const float* __restrict__ c0,
                       const u64* __restrict__ hex0,
                       u64* __restrict__ hexF, u64* __restrict__ hexS,
                       float* __restrict__ pp, int* __restrict__ ent) {
  const int p    = blockIdx.x;        // 0..63
  const int m    = p >> 4;            // member 0..3 (hidden slice of 64)
  const int grp  = p & 15;            // batch group 0..15 (stride 16 -> same XCD)
  const int bat0 = grp * BPG;
  const int hid0 = m * HPB;

  const int t   = threadIdx.x;        // 0..1023
  const int w   = t >> 6;             // wave 0..15
  const int kq  = w & 3;              // K-quarter
  const int mq  = w >> 2;             // M-quadrant (4 M-tiles each)
  const int l15 = t & 15;             // MFMA lane col
  const int hi  = (t >> 4) & 3;       // MFMA lane row-group

  const int j2 = t & 63, b2 = t >> 6;           // update role: (hid j2, batch b2) 64x16
  const int ch = t & 127, bp2 = (t >> 7) * 2;   // x staging: channel + batch-pair

  __shared__ __align__(16) short s_hxb[BPG * HXS];   // bf16 [16 b][384k+pad] = 12.5 KB
  __shared__ float s_part[4 * RPB * SPP];            // 69.6 KB K-quarter partials
  __shared__ float s_red[1024];
  __shared__ __align__(8) short s_hvalb[1024];       // bf16 h staging (own-slice path)
  __shared__ int   s_lens[NB];
  __shared__ int   s_off[BPG], s_len[BPG];

  if (t < NB) s_lens[t] = lens[t];
  __syncthreads();
  if (t < BPG) {
    int off = 0;
    for (int k = 0; k < bat0 + t; k++) off += s_lens[k];
    s_off[t] = off;
    s_len[t] = s_lens[bat0 + t];
  }
  __syncthreads();

  // ---- consumer-side zeroing of this group's FAST ring (both slots, sc0) ----
  // Kernel-start acquire invalidated L2 copies; MALL still holds last call's
  // tagged data (tags repeat across calls) -> must zero before any publish.
  #pragma unroll
  for (int z = 0; z < 2; z++) {
    const int idx = z * 1024 + t;                 // covers 2 slots x 16 b x 64 q
    const int sl = idx >> 10, bb = (idx >> 6) & 15, qq = idx & 63;
    st_sc0(hexF + ((size_t)(sl * NB) + bat0 + bb) * 64 + qq, 0ULL);
  }

  // ---- persistent W as MFMA A-fragments (zero-store flight overlaps these loads) ----
  #define LOADA(AV, MT, KC) do {                                                   \
    const int lr_   = (MT) * 16 + l15;                                             \
    const int grow_ = (lr_ >> 6) * HID + hid0 + (lr_ & 63);                        \
    const int k0_   = kq * 96 + (KC) * 32 + hi * 8;                                \
    const float* src_ = (k0_ < CIN) ? (Wih + (size_t)grow_ * CIN + k0_)            \
                                    : (Whh + (size_t)grow_ * HID + (k0_ - CIN));   \
    const float4 f0_ = *(const float4*)(src_);                                     \
    const float4 f1_ = *(const float4*)(src_ + 4);                                 \
    AV[0]=f2bf(f0_.x); AV[1]=f2bf(f0_.y); AV[2]=f2bf(f0_.z); AV[3]=f2bf(f0_.w);    \
    AV[4]=f2bf(f1_.x); AV[5]=f2bf(f1_.y); AV[6]=f2bf(f1_.z); AV[7]=f2bf(f1_.w);    \
  } while (0)
  bf16x8 a00, a01, a02, a10, a11, a12, a20, a21, a22, a30, a31, a32;
  LOADA(a00, mq*4+0, 0); LOADA(a01, mq*4+0, 1); LOADA(a02, mq*4+0, 2);
  LOADA(a10, mq*4+1, 0); LOADA(a11, mq*4+1, 1); LOADA(a12, mq*4+1, 2);
  LOADA(a20, mq*4+2, 0); LOADA(a21, mq*4+2, 1); LOADA(a22, mq*4+2, 2);
  LOADA(a30, mq*4+3, 0); LOADA(a31, mq*4+3, 1); LOADA(a32, mq*4+3, 2);

  const float bias0 = bih[0*HID + hid0 + j2] + bhh[0*HID + hid0 + j2];
  const float bias1 = bih[1*HID + hid0 + j2] + bhh[1*HID + hid0 + j2];
  const float bias2 = bih[2*HID + hid0 + j2] + bhh[2*HID + hid0 + j2];
  const float bias3 = bih[3*HID + hid0 + j2] + bhh[3*HID + hid0 + j2];

  float c_reg = c0[(size_t)(bat0 + b2) * HID + hid0 + j2];

  // ---- one-time per-group entry barrier: zeroing sealed before any publish ----
  asm volatile("s_waitcnt vmcnt(0)" ::: "memory");
  __syncthreads();
  if (t == 0) {
    __hip_atomic_fetch_add(ent + grp * 16, 1, __ATOMIC_RELAXED, __HIP_MEMORY_SCOPE_AGENT);
    while (__hip_atomic_load(ent + grp * 16, __ATOMIC_RELAXED, __HIP_MEMORY_SCOPE_AGENT) < MEMB)
      __builtin_amdgcn_s_sleep(1);
  }
  __syncthreads();

  float xp0, xp1;
  #define PREFX(S) do { \
    xp0 = ((S) < s_len[bp2+0]) ? x[(size_t)(s_off[bp2+0]+(S))*CIN+ch] : 0.f; \
    xp1 = ((S) < s_len[bp2+1]) ? x[(size_t)(s_off[bp2+1]+(S))*CIN+ch] : 0.f; \
  } while (0)

  // step-0 staging: plain bf16 u64 from hex0 (k_init stream-ordered)
  #define STAGE0() do { \
    s_hxb[(bp2+0)*HXS+ch] = f2bf(xp0); \
    s_hxb[(bp2+1)*HXS+ch] = f2bf(xp1); \
    const int b_ = t >> 6, q64_ = t & 63; \
    const u64 v_ = hex0[(size_t)(bat0 + b_) * 64 + q64_]; \
    *(u64*)&s_hxb[b_ * HXS + CIN + q64_ * 4] = v_; \
  } while (0)

  // steady-state: own slice via LDS; remote = sc0 fast poll (32x) -> agent fallback
  #define STAGE(S) do { \
    s_hxb[(bp2+0)*HXS+ch] = f2bf(xp0); \
    s_hxb[(bp2+1)*HXS+ch] = f2bf(xp1); \
    const int b_ = t >> 6, q64_ = t & 63; \
    const int mem_ = q64_ >> 4; \
    if (mem_ == m) { \
      *(u64*)&s_hxb[b_ * HXS + CIN + q64_ * 4] = \
          *(const u64*)&s_hvalb[b_ * HPB + (q64_ & 15) * 4]; \
    } else { \
      const size_t off_ = ((size_t)((((S) & 1)) * NB) + bat0 + b_) * 64 + q64_; \
      u64 v_ = ld_sc0(hexF + off_); \
      int tries_ = 0; \
      while ((v_ >> 48) != (u64)(S) && ++tries_ < 32) v_ = ld_sc0(hexF + off_); \
      if ((v_ >> 48) != (u64)(S)) { \
        do { __builtin_amdgcn_s_sleep(1); \
             v_ = __hip_atomic_load(hexS + off_, __ATOMIC_RELAXED, __HIP_MEMORY_SCOPE_AGENT); \
        } while ((v_ >> 48) != (u64)(S)); \
      } \
      short* dst_ = &s_hxb[b_ * HXS + CIN + q64_ * 4]; \
      dst_[0] = dq12((int)(v_        & 0xFFF)); \
      dst_[1] = dq12((int)((v_ >> 12) & 0xFFF)); \
      dst_[2] = dq12((int)((v_ >> 24) & 0xFFF)); \
      dst_[3] = dq12((int)((v_ >> 36) & 0xFFF)); \
    } \
  } while (0)

  PREFX(0);
  STAGE0();
  __syncthreads();

  for (int s = 0; s < TST; s++) {
    // ---- gate K-quarter partials via MFMA: 3 B-frags x 4 M-tiles per wave ----
    f32x4 d0 = {0.f,0.f,0.f,0.f}, d1 = {0.f,0.f,0.f,0.f};
    f32x4 d2 = {0.f,0.f,0.f,0.f}, d3 = {0.f,0.f,0.f,0.f};
    {
      const short* hxb = s_hxb + l15 * HXS + kq * 96 + hi * 8;
      bf16x8 bv;
      bv = *(const bf16x8*)(hxb + 0);
      d0 = __builtin_amdgcn_mfma_f32_16x16x32_bf16(a00, bv, d0, 0, 0, 0);
      d1 = __builtin_amdgcn_mfma_f32_16x16x32_bf16(a10, bv, d1, 0, 0, 0);
      d2 = __builtin_amdgcn_mfma_f32_16x16x32_bf16(a20, bv, d2, 0, 0, 0);
      d3 = __builtin_amdgcn_mfma_f32_16x16x32_bf16(a30, bv, d3, 0, 0, 0);
      bv = *(const bf16x8*)(hxb + 32);
      d0 = __builtin_amdgcn_mfma_f32_16x16x32_bf16(a01, bv, d0, 0, 0, 0);
      d1 = __builtin_amdgcn_mfma_f32_16x16x32_bf16(a11, bv, d1, 0, 0, 0);
      d2 = __builtin_amdgcn_mfma_f32_16x16x32_bf16(a21, bv, d2, 0, 0, 0);
      d3 = __builtin_amdgcn_mfma_f32_16x16x32_bf16(a31, bv, d3, 0, 0, 0);
      bv = *(const bf16x8*)(hxb + 64);
      d0 = __builtin_amdgcn_mfma_f32_16x16x32_bf16(a02, bv, d0, 0, 0, 0);
      d1 = __builtin_amdgcn_mfma_f32_16x16x32_bf16(a12, bv, d1, 0, 0, 0);
      d2 = __builtin_amdgcn_mfma_f32_16x16x32_bf16(a22, bv, d2, 0, 0, 0);
      d3 = __builtin_amdgcn_mfma_f32_16x16x32_bf16(a32, bv, d3, 0, 0, 0);
    }
    if (s < TST - 1) PREFX(s + 1);

    // C layout (m89-verified): col = lane&15, local row = 16*mt + hi*4 + reg
    {
      float* spc = s_part + (size_t)(kq * RPB + mq * 64 + hi * 4) * SPP + l15;
      spc[(0*16 + 0)*SPP] = d0[0]; spc[(0*16 + 1)*SPP] = d0[1];
      spc[(0*16 + 2)*SPP] = d0[2]; spc[(0*16 + 3)*SPP] = d0[3];
      spc[(1*16 + 0)*SPP] = d1[0]; spc[(1*16 + 1)*SPP] = d1[1];
      spc[(1*16 + 2)*SPP] = d1[2]; spc[(1*16 + 3)*SPP] = d1[3];
      spc[(2*16 + 0)*SPP] = d2[0]; spc[(2*16 + 1)*SPP] = d2[1];
      spc[(2*16 + 2)*SPP] = d2[2]; spc[(2*16 + 3)*SPP] = d2[3];
      spc[(3*16 + 0)*SPP] = d3[0]; spc[(3*16 + 1)*SPP] = d3[1];
      spc[(3*16 + 2)*SPP] = d3[2]; spc[(3*16 + 3)*SPP] = d3[3];
    }
    __syncthreads();

    // ---- update: thread (j2,b2) sums 4 K-quarters for its 4 gate rows ----
    float g0 = bias0, g1 = bias1, g2 = bias2, g3 = bias3;
    #pragma unroll
    for (int q = 0; q < 4; q++) {
      const float* spq = s_part + (size_t)(q * RPB + j2) * SPP + b2;
      g0 += spq[(0 * 64) * SPP];
      g1 += spq[(1 * 64) * SPP];
      g2 += spq[(2 * 64) * SPP];
      g3 += spq[(3 * 64) * SPP];
    }
    c_reg = fmaf(sigm(g1), c_reg, sigm(g0) * tanh_(g2));
    const float h = sigm(g3) * tanh_(c_reg);

    // ---- IMMEDIATE double publish: sc0 (fast, XCD L2) then agent mirror ----
    {
      const int q  = q12(h);
      const int qp = q | (__shfl_xor(q, 1) << 12);
      const int qo = __shfl_xor(qp, 2);
      if ((t & 3) == 0) {
        const u64 v = ((u64)(s + 1) << 48) |
                      ((u64)(unsigned)(qo & 0xFFFFFF) << 24) |
                      (u64)(unsigned)(qp & 0xFFFFFF);
        const size_t off = ((size_t)(((s + 1) & 1) * NB) + bat0 + b2) * 64 +
                           (hid0 >> 2) + (j2 >> 2);
        st_sc0(hexF + off, v);
        __hip_atomic_store(hexS + off, v, __ATOMIC_RELAXED, __HIP_MEMORY_SCOPE_AGENT);
      }
    }
    s_hvalb[b2 * HPB + j2] = f2bf(h);
    s_red[b2 * HPB + j2]   = (bat0 + b2 < s_lens[s]) ? h : 0.f;
    __syncthreads();

    // masked partial for output row s (overlaps other threads' STAGE polling)
    if (t >= 512 && t < 512 + HPB) {
      const int jl = t - 512;
      float ps = 0.f;
      #pragma unroll
      for (int b = 0; b < BPG; b++) ps += s_red[b * HPB + jl];
      pp[(((size_t)s * GRPS + grp) * MEMB + m) * HPB + jl] = ps;
    }

    if (s == TST - 1) break;

    STAGE(s + 1);
    __syncthreads();
  }
}

// ---------------- masked batch-mean + FC ----------------
__global__ void k_out(const float* __restrict__ pp, const int* __restrict__ lens,
                      const float* __restrict__ fcW, const float* __restrict__ fcb,
                      float* __restrict__ out) {
  const int i = blockIdx.x, t = threadIdx.x;
  __shared__ float s_fc[HID];
  const int cnt = min(lens[i], NB);
  const int m = t >> 6, jl = t & 63;             // hid = t
  float a = 0.f;
  const float* base = pp + ((size_t)i * GRPS * MEMB + m) * HPB + jl;
  #pragma unroll 4
  for (int g = 0; g < GRPS; g++) a += base[(size_t)g * MEMB * HPB];
  s_fc[t] = a / (float)cnt;
  __syncthreads();
  for (int n = t; n < NCLS; n += 256) {
    float acc = fcb[n];
    const float4* w4 = (const float4*)(fcW + (size_t)n * HID);
    #pragma unroll 8
    for (int k4 = 0; k4 < HID / 4; k4++) {
      const float4 wv = w4[k4];
      acc = fmaf(s_fc[4*k4+0], wv.x, acc);
      acc = fmaf(s_fc[4*k4+1], wv.y, acc);
      acc = fmaf(s_fc[4*k4+2], wv.z, acc);
      acc = fmaf(s_fc[4*k4+3], wv.w, acc);
    }
    out[(size_t)i * NCLS + n] = acc;
  }
}

extern "C" void kernel_launch(void* const* d_in, const int* in_sizes, int n_in,
                              void* d_out, int out_size, void* d_ws, size_t ws_size,
                              hipStream_t stream) {
  const float* x    = (const float*)d_in[0];
  const int*   lens = (const int*)  d_in[1];
  const float* Wih  = (const float*)d_in[2];
  const float* Whh  = (const float*)d_in[3];
  const float* bih  = (const float*)d_in[4];
  const float* bhh  = (const float*)d_in[5];
  const float* w1h  = (const float*)d_in[6];
  const float* w2h  = (const float*)d_in[7];
  const float* w1c  = (const float*)d_in[8];
  const float* w2c  = (const float*)d_in[9];
  const float* fcW  = (const float*)d_in[10];
  const float* fcb  = (const float*)d_in[11];
  float* out = (float*)d_out;

  char* ws = (char*)d_ws;
  float* sums = (float*)(ws + WS_SUMS);
  u64*   hex0 = (u64*)  (ws + WS_HEX0);
  u64*   hexS = (u64*)  (ws + WS_HEXS);
  int*   ent  = (int*)  (ws + WS_ENT);
  u64*   hexF = (u64*)  (ws + WS_HEXF);
  float* c0   = (float*)(ws + WS_C0);
  float* pp   = (float*)(ws + WS_PP);

  // zero slow ring + entry counters every call (hexF is zeroed consumer-side
  // in-kernel with sc0 stores -- memset wouldn't be visible at that scope anyway)
  hipMemsetAsync(hexS, 0, 2 * NB * 64 * sizeof(u64) + 1024, stream);
  k_segsum<<<NB, 256, 0, stream>>>(x, lens, sums);
  k_init  <<<NB, 256, 0, stream>>>(sums, w1h, w2h, w1c, w2c, hex0, c0);
  k_lstm  <<<GRPS * MEMB, 1024, 0, stream>>>(x, lens, Wih, Whh, bih, bhh, c0,
                                             hex0, hexF, hexS, pp, ent);
  k_out   <<<NB, 256, 0, stream>>>(pp, lens, fcW, fcb, out);
}